// Round 4
// baseline (5635.188 us; speedup 1.0000x reference)
//
#include <hip/hip_runtime.h>
#include <hip/hip_bf16.h>

// MLA forward, round 4: spill-free c-split MFMA attention + bf16 MFMA GEMMs.
// B=2 S=2048 D=2048 H=16 NOPE=128 ROPE=64 V=128 C=512
#define B_ 2
#define S_ 2048
#define H_ 16

typedef unsigned short ushort_t;
typedef unsigned int uint_t;
typedef __attribute__((ext_vector_type(8))) short bf16x8;
typedef __attribute__((ext_vector_type(4))) float f32x4;

__device__ __forceinline__ ushort_t f2bf(float f) {
    uint_t u = __float_as_uint(f);
    return (ushort_t)((u + 0x7fffu + ((u >> 16) & 1u)) >> 16);
}
__device__ __forceinline__ float bf2f(ushort_t v) {
    return __uint_as_float(((uint_t)v) << 16);
}

// ---------------------------------------------------------------------------
// f32 -> bf16 cast (n multiple of 1024)
// ---------------------------------------------------------------------------
__global__ __launch_bounds__(256) void cast_bf16(const float* __restrict__ src,
                                                 ushort_t* __restrict__ dst, int n)
{
    int i = (blockIdx.x * 256 + threadIdx.x) * 4;
    if (i < n) {
        float4 v = *(const float4*)(src + i);
        ushort_t pk[4] = { f2bf(v.x), f2bf(v.y), f2bf(v.z), f2bf(v.w) };
        *(uint2*)(dst + i) = *(const uint2*)pk;
    }
}

// ---------------------------------------------------------------------------
// bf16 MFMA GEMM: C[M,N] = A[M,K] @ B[N,K]^T. M,N %128==0, K%64==0.
// 128x128 tile, BK=64, 256 thr / 4 waves (2x2), 16 mfma/wave/ks.
// ---------------------------------------------------------------------------
__global__ __launch_bounds__(256, 2) void gemm_bf16(const ushort_t* __restrict__ A,
                                                    const ushort_t* __restrict__ Bm,
                                                    float* __restrict__ Cf,
                                                    ushort_t* __restrict__ Cb,
                                                    int M, int N, int K, int outBf)
{
    __shared__ __align__(16) ushort_t As[128*72];
    __shared__ __align__(16) ushort_t Bs[128*72];
    const int tid = threadIdx.x;
    const int wv = tid >> 6, lane = tid & 63, l16 = lane & 15, quad = lane >> 4;
    const int wm = wv >> 1, wn = wv & 1;
    const int m0 = blockIdx.y * 128, n0 = blockIdx.x * 128;
    const int row = tid >> 1, kh = (tid & 1) * 32;
    const ushort_t* Ag = A  + (size_t)(m0 + row) * K + kh;
    const ushort_t* Bg = Bm + (size_t)(n0 + row) * K + kh;

    f32x4 acc[16];
#pragma unroll
    for (int i = 0; i < 16; i++) acc[i] = (f32x4)(0.f);

    for (int k0 = 0; k0 < K; k0 += 64) {
        uint4 av[4], bv[4];
#pragma unroll
        for (int p = 0; p < 4; p++) {
            av[p] = *(const uint4*)(Ag + k0 + p*8);
            bv[p] = *(const uint4*)(Bg + k0 + p*8);
        }
        __syncthreads();
#pragma unroll
        for (int p = 0; p < 4; p++) {
            *(uint4*)(As + row*72 + kh + p*8) = av[p];
            *(uint4*)(Bs + row*72 + kh + p*8) = bv[p];
        }
        __syncthreads();
#pragma unroll
        for (int ks = 0; ks < 2; ks++) {
            bf16x8 af[4], bfr[4];
#pragma unroll
            for (int mt = 0; mt < 4; mt++)
                af[mt] = *(const bf16x8*)(As + (wm*64 + mt*16 + l16)*72 + ks*32 + quad*8);
#pragma unroll
            for (int nt = 0; nt < 4; nt++)
                bfr[nt] = *(const bf16x8*)(Bs + (wn*64 + nt*16 + l16)*72 + ks*32 + quad*8);
#pragma unroll
            for (int mt = 0; mt < 4; mt++)
#pragma unroll
                for (int nt = 0; nt < 4; nt++)
                    acc[mt*4+nt] = __builtin_amdgcn_mfma_f32_16x16x32_bf16(af[mt], bfr[nt], acc[mt*4+nt], 0, 0, 0);
        }
    }
#pragma unroll
    for (int mt = 0; mt < 4; mt++)
#pragma unroll
        for (int nt = 0; nt < 4; nt++)
#pragma unroll
            for (int r = 0; r < 4; r++) {
                size_t rr = m0 + wm*64 + mt*16 + quad*4 + r;
                int cc = n0 + wn*64 + nt*16 + l16;
                if (outBf) Cb[rr*N + cc] = f2bf(acc[mt*4+nt][r]);
                else       Cf[rr*N + cc] = acc[mt*4+nt][r];
            }
}

// ---------------------------------------------------------------------------
// f32 GEMM for kv-proj (kept f32 for rmsnorm accuracy).  N=576.
// ---------------------------------------------------------------------------
__global__ __launch_bounds__(256) void gemm_nt(const float* __restrict__ A,
                                               const float* __restrict__ Bm,
                                               float* __restrict__ Cm,
                                               int M, int N, int K,
                                               int lda, int ldb, int ldc)
{
    __shared__ float As[16][68];
    __shared__ float Bs[16][68];
    const int tid = threadIdx.x;
    const int m0 = blockIdx.y * 64, n0 = blockIdx.x * 64;
    const int lr = tid >> 2;
    const int lc = (tid & 3) << 2;
    const int ty = tid >> 4, tx = tid & 15;
    const float* Ag = A  + (m0 + lr) * lda + lc;
    const float* Bg = Bm + (n0 + lr) * ldb + lc;

    float acc[4][4];
#pragma unroll
    for (int i = 0; i < 4; i++)
#pragma unroll
        for (int j = 0; j < 4; j++) acc[i][j] = 0.f;

    for (int k0 = 0; k0 < K; k0 += 16) {
        float4 av = *(const float4*)(Ag + k0);
        float4 bv = *(const float4*)(Bg + k0);
        __syncthreads();
        As[lc+0][lr] = av.x; As[lc+1][lr] = av.y; As[lc+2][lr] = av.z; As[lc+3][lr] = av.w;
        Bs[lc+0][lr] = bv.x; Bs[lc+1][lr] = bv.y; Bs[lc+2][lr] = bv.z; Bs[lc+3][lr] = bv.w;
        __syncthreads();
#pragma unroll
        for (int kk = 0; kk < 16; kk++) {
            float4 a = *(const float4*)&As[kk][ty*4];
            float4 b = *(const float4*)&Bs[kk][tx*4];
            acc[0][0] += a.x*b.x; acc[0][1] += a.x*b.y; acc[0][2] += a.x*b.z; acc[0][3] += a.x*b.w;
            acc[1][0] += a.y*b.x; acc[1][1] += a.y*b.y; acc[1][2] += a.y*b.z; acc[1][3] += a.y*b.w;
            acc[2][0] += a.z*b.x; acc[2][1] += a.z*b.y; acc[2][2] += a.z*b.z; acc[2][3] += a.z*b.w;
            acc[3][0] += a.w*b.x; acc[3][1] += a.w*b.y; acc[3][2] += a.w*b.z; acc[3][3] += a.w*b.w;
        }
    }
#pragma unroll
    for (int i = 0; i < 4; i++) {
        float4 r; r.x = acc[i][0]; r.y = acc[i][1]; r.z = acc[i][2]; r.w = acc[i][3];
        *(float4*)(Cm + (m0 + ty*4 + i) * ldc + n0 + tx*4) = r;
    }
}

// ---------------------------------------------------------------------------
// prep: wbkT[h][c][d] = bf16(wkv_b[h][d][c]); wbvB[h][dv][c] = bf16(wkv_b[h][128+dv][c])
// ---------------------------------------------------------------------------
__global__ __launch_bounds__(256) void prep_wb(const float* __restrict__ wkv_b,
                                               ushort_t* __restrict__ wbkT,
                                               ushort_t* __restrict__ wbvB)
{
    int u = blockIdx.x * 256 + threadIdx.x;
    {
        int h = u >> 16, rem = u & 65535, c = rem >> 7, d = rem & 127;
        wbkT[u] = f2bf(wkv_b[h*131072 + d*512 + c]);
    }
    {
        int h = u >> 16, rem = u & 65535;
        wbvB[u] = f2bf(wkv_b[h*131072 + 65536 + rem]);
    }
}

// ---------------------------------------------------------------------------
// kvr (BS x 576) -> kvnb bf16, kvnT bf16 [b][c][t], kpeb bf16
// ---------------------------------------------------------------------------
__global__ __launch_bounds__(256) void kv_norm_rope(const float* __restrict__ kvr,
                                                    const float* __restrict__ w,
                                                    const float* __restrict__ cosT,
                                                    const float* __restrict__ sinT,
                                                    ushort_t* __restrict__ kvnb,
                                                    ushort_t* __restrict__ kvnT,
                                                    ushort_t* __restrict__ kpeb)
{
    const int bs   = blockIdx.x * 4 + (threadIdx.x >> 6);
    const int lane = threadIdx.x & 63;
    const int s    = bs & (S_ - 1);
    const float* row = kvr + bs * 576;

    float4 v0 = *(const float4*)(row + lane*8);
    float4 v1 = *(const float4*)(row + lane*8 + 4);
    float ss = v0.x*v0.x + v0.y*v0.y + v0.z*v0.z + v0.w*v0.w
             + v1.x*v1.x + v1.y*v1.y + v1.z*v1.z + v1.w*v1.w;
#pragma unroll
    for (int off = 32; off >= 1; off >>= 1) ss += __shfl_xor(ss, off);
    const float rs = rsqrtf(ss * (1.0f/512.0f) + 1e-6f);

    float4 w0 = *(const float4*)(w + lane*8);
    float4 w1 = *(const float4*)(w + lane*8 + 4);
    float o[8];
    o[0] = v0.x*rs*w0.x; o[1] = v0.y*rs*w0.y; o[2] = v0.z*rs*w0.z; o[3] = v0.w*rs*w0.w;
    o[4] = v1.x*rs*w1.x; o[5] = v1.y*rs*w1.y; o[6] = v1.z*rs*w1.z; o[7] = v1.w*rs*w1.w;

    ushort_t pk[8];
#pragma unroll
    for (int p = 0; p < 8; p++) pk[p] = f2bf(o[p]);
    *(uint4*)(kvnb + (size_t)bs*512 + lane*8) = *(const uint4*)pk;

    const int bb = bs >> 11, t = bs & 2047;
    ushort_t* base = kvnT + ((size_t)(bb*512 + lane*8))*2048 + t;
#pragma unroll
    for (int k = 0; k < 8; k++) base[k*2048] = pk[k];

    if (lane < 32) {
        float xr = row[512 + 2*lane], xi = row[512 + 2*lane + 1];
        float c  = cosT[s*32 + lane], sn = sinT[s*32 + lane];
        ushort_t p2[2] = { f2bf(xr*c - xi*sn), f2bf(xr*sn + xi*c) };
        *(uint_t*)(kpeb + (size_t)bs*64 + 2*lane) = *(const uint_t*)p2;
    }
}

// ---------------------------------------------------------------------------
// MFMA flash attention v2: 512 thr / 8 waves. wave = (rg = wv>>1: 16 rows,
// cg = wv&1: 256-c half). Scores computed transposed (S^T = mfma(Kfrag,Qfrag))
// redundantly per cg pair; softmax state = scalar m,l per lane (row = l16).
// PV via 16x16x32 with zero-padded upper K (TK=16). o[16] f32x4 per wave.
// LDS 64768 B: kt 16x584 | vt 512x40 | pt 64x40 (pads zeroed once).
// ---------------------------------------------------------------------------
__global__ __launch_bounds__(512, 2) void attn_mfma(
    const ushort_t* __restrict__ qb,
    const ushort_t* __restrict__ kvnb,
    const ushort_t* __restrict__ kpeb,
    const ushort_t* __restrict__ kvnT,
    const float* __restrict__ cosT,
    const float* __restrict__ sinT,
    const ushort_t* __restrict__ wbkT,
    const ushort_t* __restrict__ wbvB,
    ushort_t* __restrict__ ovb)
{
    const int q0 = blockIdx.x * 64;
    const int h  = blockIdx.y;
    const int b  = blockIdx.z;
    const int tid  = threadIdx.x;
    const int wv   = tid >> 6;
    const int lane = tid & 63;
    const int l16  = lane & 15;
    const int quad = lane >> 4;
    const int rg   = wv >> 1;          // row-group 0..3 (16 rows each)
    const int cg   = wv & 1;           // c-half 0..1 (256 each)
    const float scale = 0.07216878364870323f;   // 192^-0.5

    __shared__ __align__(16) ushort_t lds[32384];   // 64768 B
    ushort_t* kt = lds;                 // 16 x 584
    ushort_t* vt = lds + 9344;          // 512 x 40 (t 0..15 data, 16..39 zero)
    ushort_t* pt = lds + 29824;         // 64 x 40  (t 0..15 data, 16..39 zero)

    const int mrowb = rg*16 + l16;      // block-local A-frag row
    const int sgr   = q0 + mrowb;       // global row for A-frag
    const int irow  = rg*16 + quad*4;   // block-local C-layout row base

    // ===== phase A: build Q A-frags qf[18] =====
    ushort_t* halfbuf = lds;            // 64 x 264 overlay
    ushort_t* qn = lds + 16896;         // 64 x 136 overlay

    for (int u = tid; u < 1024; u += 512) {
        int r = u >> 4, c8 = u & 15;
        *(uint4*)(qn + r*136 + c8*8) =
            *(const uint4*)(qb + (size_t)(b*S_ + q0 + r)*3072 + h*192 + c8*8);
    }
    __syncthreads();

    bf16x8 qa[4], qf[18];
#pragma unroll
    for (int ks = 0; ks < 4; ks++)
        qa[ks] = *(const bf16x8*)(qn + mrowb*136 + ks*32 + quad*8);

    const ushort_t* wbk_h = wbkT + h*65536;
#pragma unroll 1
    for (int half = 0; half < 2; half++) {
        f32x4 ab[16];
#pragma unroll
        for (int n = 0; n < 16; n++) ab[n] = (f32x4)(0.f);
#pragma unroll 1
        for (int n = 0; n < 16; n++) {
            const ushort_t* wp = wbk_h + (half*256 + n*16 + l16)*128 + quad*8;
#pragma unroll
            for (int ks = 0; ks < 4; ks++) {
                bf16x8 bw = *(const bf16x8*)(wp + ks*32);
                ab[n] = __builtin_amdgcn_mfma_f32_16x16x32_bf16(qa[ks], bw, ab[n], 0, 0, 0);
            }
        }
#pragma unroll
        for (int n = 0; n < 16; n++)
#pragma unroll
            for (int r = 0; r < 4; r++)
                halfbuf[(irow + r)*264 + n*16 + l16] = f2bf(ab[n][r] * scale);
#pragma unroll
        for (int ks = 0; ks < 8; ks++)
            qf[half*8 + ks] = *(const bf16x8*)(halfbuf + mrowb*264 + ks*32 + quad*8);
    }

    // pe -> qf[16..17]
#pragma unroll
    for (int kk = 0; kk < 2; kk++) {
        int off = kk*32 + quad*8;
        uint4 pv4 = *(const uint4*)(qb + (size_t)(b*S_ + sgr)*3072 + h*192 + 128 + off);
        const ushort_t* pe = (const ushort_t*)&pv4;
        ushort_t pk[8];
#pragma unroll
        for (int u2 = 0; u2 < 4; u2++) {
            float xr = bf2f(pe[2*u2]), xi = bf2f(pe[2*u2+1]);
            int pi = (off >> 1) + u2;
            float c = cosT[sgr*32 + pi], sn = sinT[sgr*32 + pi];
            pk[2*u2]   = f2bf((xr*c  - xi*sn) * scale);
            pk[2*u2+1] = f2bf((xr*sn + xi*c ) * scale);
        }
        qf[16 + kk] = *(const bf16x8*)pk;
    }
    __syncthreads();   // overlays dead

    // zero vt+pt region (pads stay zero; data cols rewritten each iter)
    for (int u = tid; u < 11520; u += 512) ((uint_t*)lds)[4672 + u] = 0;
    __syncthreads();

    // ===== flash main loop, TK=16 =====
    f32x4 o[16];
#pragma unroll
    for (int n = 0; n < 16; n++) o[n] = (f32x4)(0.f);
    float m_s = -1e30f, l_s = 0.f;
    const int rglob = q0 + rg*16 + l16;    // softmax row owned by this lane
    const int lb = lane & 48;
    const int niter = (q0 >> 4) + 4;

#pragma unroll 1
    for (int it = 0; it < niter; it++) {
        const int t0 = it * 16;
        for (int u = tid; u < 1152; u += 512) {
            int j = u / 72, cc = u - j*72;
            const ushort_t* src = (cc < 64)
                ? (kvnb + (size_t)(b*S_ + t0 + j)*512 + cc*8)
                : (kpeb + (size_t)(b*S_ + t0 + j)*64 + (cc - 64)*8);
            *(uint4*)(kt + j*584 + cc*8) = *(const uint4*)src;
        }
        for (int u = tid; u < 1024; u += 512) {
            int c = u >> 1, part = u & 1;
            *(uint4*)(vt + c*40 + part*8) =
                *(const uint4*)(kvnT + (size_t)(b*512 + c)*2048 + t0 + part*8);
        }
        __syncthreads();

        // S^T[t][r] via mfma(A=K, B=Q)
        f32x4 s = (f32x4)(0.f);
#pragma unroll
        for (int ks = 0; ks < 18; ks++) {
            bf16x8 kf = *(const bf16x8*)(kt + l16*584 + ks*32 + quad*8);
            s = __builtin_amdgcn_mfma_f32_16x16x32_bf16(kf, qf[ks], s, 0, 0, 0);
        }

        // softmax over t for row rglob (lane holds t = t0+quad*4+reg, r = l16)
        float pv[4];
        float mx = -1e30f;
#pragma unroll
        for (int reg = 0; reg < 4; reg++) {
            bool ok = (t0 + quad*4 + reg) <= rglob;
            pv[reg] = ok ? s[reg] : -1e30f;
            mx = fmaxf(mx, pv[reg]);
        }
        mx = fmaxf(mx, __shfl_xor(mx, 16));
        mx = fmaxf(mx, __shfl_xor(mx, 32));
        float mn = fmaxf(m_s, mx);
        float al = __expf(m_s - mn);
        m_s = mn;
        float ps = 0.f;
#pragma unroll
        for (int reg = 0; reg < 4; reg++) {
            pv[reg] = ((t0 + quad*4 + reg) <= rglob) ? __expf(pv[reg] - mn) : 0.f;
            ps += pv[reg];
        }
        ps += __shfl_xor(ps, 16);
        ps += __shfl_xor(ps, 32);
        l_s = l_s * al + ps;

        // alpha vector for o rows (row = quad*4+reg)
        f32x4 alv;
#pragma unroll
        for (int reg = 0; reg < 4; reg++) alv[reg] = __shfl(al, lb + quad*4 + reg, 64);
#pragma unroll
        for (int n = 0; n < 16; n++) o[n] *= alv;

        // P^T -> pt[r][t] (single b64 write), read back A-frag (in-wave)
        ushort_t pk[4];
#pragma unroll
        for (int reg = 0; reg < 4; reg++) pk[reg] = f2bf(pv[reg]);
        *(uint2*)(pt + (rg*16 + l16)*40 + quad*4) = *(const uint2*)pk;
        bf16x8 ap = *(const bf16x8*)(pt + (rg*16 + l16)*40 + quad*8);

        // PV: o[n] += P[r][t] * V[t][c], c = cg*256 + n*16 + l16
#pragma unroll
        for (int n = 0; n < 16; n++) {
            bf16x8 bv = *(const bf16x8*)(vt + (cg*256 + n*16 + l16)*40 + quad*8);
            o[n] = __builtin_amdgcn_mfma_f32_16x16x32_bf16(ap, bv, o[n], 0, 0, 0);
        }
        __syncthreads();
    }

    // ===== epilogue: o_v = (o/l) @ wbv^T, partial per cg then LDS reduce =====
    float linv = 1.f / l_s;
    f32x4 rlv;
#pragma unroll
    for (int reg = 0; reg < 4; reg++) rlv[reg] = __shfl(linv, lb + quad*4 + reg, 64);

    const ushort_t* wbv_h = wbvB + h*65536;
    ushort_t* obw = lds + wv*2176;       // per-wave 16 x 136
    f32x4 acc2[8];
#pragma unroll
    for (int n = 0; n < 8; n++) acc2[n] = (f32x4)(0.f);

#pragma unroll 1
    for (int sub = 0; sub < 2; sub++) {
#pragma unroll
        for (int n = 0; n < 8; n++)
#pragma unroll
            for (int r = 0; r < 4; r++)
                obw[(quad*4 + r)*136 + n*16 + l16] = f2bf(o[sub*8 + n][r] * rlv[r]);
#pragma unroll
        for (int ks = 0; ks < 4; ks++) {
            bf16x8 af = *(const bf16x8*)(obw + l16*136 + ks*32 + quad*8);
#pragma unroll
            for (int n2 = 0; n2 < 8; n2++) {
                bf16x8 bw = *(const bf16x8*)(wbv_h + (n2*16 + l16)*512 + cg*256 + sub*128 + ks*32 + quad*8);
                acc2[n2] = __builtin_amdgcn_mfma_f32_16x16x32_bf16(af, bw, acc2[n2], 0, 0, 0);
            }
        }
    }
    __syncthreads();
    float* red = (float*)lds;            // 64 x 132 f32
    if (cg == 0) {
#pragma unroll
        for (int n2 = 0; n2 < 8; n2++)
#pragma unroll
            for (int r = 0; r < 4; r++)
                red[(irow + r)*132 + n2*16 + l16] = acc2[n2][r];
    }
    __syncthreads();
    if (cg == 1) {
#pragma unroll
        for (int n2 = 0; n2 < 8; n2++)
#pragma unroll
            for (int r = 0; r < 4; r++) {
                float v = red[(irow + r)*132 + n2*16 + l16] + acc2[n2][r];
                ovb[(size_t)(b*S_ + q0 + irow + r)*2048 + h*128 + n2*16 + l16] = f2bf(v);
            }
    }
}

// ---------------------------------------------------------------------------
extern "C" void kernel_launch(void* const* d_in, const int* in_sizes, int n_in,
                              void* d_out, int out_size, void* d_ws, size_t ws_size,
                              hipStream_t stream) {
    const float* x     = (const float*)d_in[0];
    const float* cosT  = (const float*)d_in[1];
    const float* sinT  = (const float*)d_in[2];
    // d_in[3] mask: unused (causality applied directly)
    const float* wq    = (const float*)d_in[4];
    const float* wkv_a = (const float*)d_in[5];
    const float* kvw   = (const float*)d_in[6];
    const float* wkv_b = (const float*)d_in[7];
    const float* wo    = (const float*)d_in[8];
    float* out = (float*)d_out;

    // workspace layout (~102 MB)
    ushort_t* qb   = (ushort_t*)d_ws;       // 4096x3072 bf16
    ushort_t* xb   = qb   + 12582912;       // 4096x2048
    ushort_t* wqb  = xb   + 8388608;        // 3072x2048
    ushort_t* wob  = wqb  + 6291456;        // 2048x2048
    ushort_t* ovb  = wob  + 4194304;        // 4096x2048
    ushort_t* kvnb = ovb  + 8388608;        // 4096x512
    ushort_t* kpeb = kvnb + 2097152;        // 4096x64
    ushort_t* kvnT = kpeb + 262144;         // 2x512x2048
    ushort_t* wbkT = kvnT + 2097152;        // 16x512x128
    ushort_t* wbvB = wbkT + 1048576;        // 16x128x512
    float*    kvr  = (float*)(wbvB + 1048576);  // 4096x576 f32

    dim3 blk(256);
    cast_bf16<<<dim3(8192), blk, 0, stream>>>(x,  xb,  8388608);
    cast_bf16<<<dim3(6144), blk, 0, stream>>>(wq, wqb, 6291456);
    cast_bf16<<<dim3(4096), blk, 0, stream>>>(wo, wob, 4194304);
    prep_wb<<<dim3(4096), blk, 0, stream>>>(wkv_b, wbkT, wbvB);
    // qb = xb @ wqb^T (bf16 out)
    gemm_bf16<<<dim3(3072/128, 4096/128), blk, 0, stream>>>(xb, wqb, nullptr, qb, 4096, 3072, 2048, 1);
    // kvr = x @ wkv_a^T (f32)
    gemm_nt<<<dim3(576/64, 4096/64), blk, 0, stream>>>(x, wkv_a, kvr, 4096, 576, 2048, 2048, 2048, 576);
    kv_norm_rope<<<dim3(4096/4), blk, 0, stream>>>(kvr, kvw, cosT, sinT, kvnb, kvnT, kpeb);
    attn_mfma<<<dim3(S_/64, H_, B_), dim3(512), 0, stream>>>(qb, kvnb, kpeb, kvnT, cosT, sinT, wbkT, wbvB, ovb);
    // out = ovb @ wob^T (f32 out)
    gemm_bf16<<<dim3(2048/128, 4096/128), blk, 0, stream>>>(ovb, wob, out, nullptr, 4096, 2048, 2048, 0);
}

// Round 6
// 2408.768 us; speedup vs baseline: 2.3394x; 2.3394x over previous
//
#include <hip/hip_runtime.h>
#include <hip/hip_bf16.h>

// MLA forward, round 6: round-5 static-index attention + barriers/fences on
// every LDS write->read round-trip (phase-A halfbuf had a cg-pair race and
// TBAA-reorder hazard once unrolled; epilogue obw same; pt gets a fence).
// B=2 S=2048 D=2048 H=16 NOPE=128 ROPE=64 V=128 C=512
#define B_ 2
#define S_ 2048
#define H_ 16

typedef unsigned short ushort_t;
typedef unsigned int uint_t;
typedef __attribute__((ext_vector_type(8))) short bf16x8;
typedef __attribute__((ext_vector_type(4))) float f32x4;

__device__ __forceinline__ ushort_t f2bf(float f) {
    uint_t u = __float_as_uint(f);
    return (ushort_t)((u + 0x7fffu + ((u >> 16) & 1u)) >> 16);
}
__device__ __forceinline__ float bf2f(ushort_t v) {
    return __uint_as_float(((uint_t)v) << 16);
}

// ---------------------------------------------------------------------------
// f32 -> bf16 cast
// ---------------------------------------------------------------------------
__global__ __launch_bounds__(256) void cast_bf16(const float* __restrict__ src,
                                                 ushort_t* __restrict__ dst, int n)
{
    int i = (blockIdx.x * 256 + threadIdx.x) * 4;
    if (i < n) {
        float4 v = *(const float4*)(src + i);
        ushort_t pk[4] = { f2bf(v.x), f2bf(v.y), f2bf(v.z), f2bf(v.w) };
        *(uint2*)(dst + i) = *(const uint2*)pk;
    }
}

// ---------------------------------------------------------------------------
// bf16 MFMA GEMM: C[M,N] = A[M,K] @ B[N,K]^T. M,N %128==0, K%64==0.
// ---------------------------------------------------------------------------
__global__ __launch_bounds__(256, 2) void gemm_bf16(const ushort_t* __restrict__ A,
                                                    const ushort_t* __restrict__ Bm,
                                                    float* __restrict__ Cf,
                                                    ushort_t* __restrict__ Cb,
                                                    int M, int N, int K, int outBf)
{
    __shared__ __align__(16) ushort_t As[128*72];
    __shared__ __align__(16) ushort_t Bs[128*72];
    const int tid = threadIdx.x;
    const int wv = tid >> 6, lane = tid & 63, l16 = lane & 15, quad = lane >> 4;
    const int wm = wv >> 1, wn = wv & 1;
    const int m0 = blockIdx.y * 128, n0 = blockIdx.x * 128;
    const int row = tid >> 1, kh = (tid & 1) * 32;
    const ushort_t* Ag = A  + (size_t)(m0 + row) * K + kh;
    const ushort_t* Bg = Bm + (size_t)(n0 + row) * K + kh;

    f32x4 acc[16];
#pragma unroll
    for (int i = 0; i < 16; i++) acc[i] = (f32x4)(0.f);

    for (int k0 = 0; k0 < K; k0 += 64) {
        uint4 av[4], bv[4];
#pragma unroll
        for (int p = 0; p < 4; p++) {
            av[p] = *(const uint4*)(Ag + k0 + p*8);
            bv[p] = *(const uint4*)(Bg + k0 + p*8);
        }
        __syncthreads();
#pragma unroll
        for (int p = 0; p < 4; p++) {
            *(uint4*)(As + row*72 + kh + p*8) = av[p];
            *(uint4*)(Bs + row*72 + kh + p*8) = bv[p];
        }
        __syncthreads();
#pragma unroll
        for (int ks = 0; ks < 2; ks++) {
            bf16x8 af[4], bfr[4];
#pragma unroll
            for (int mt = 0; mt < 4; mt++)
                af[mt] = *(const bf16x8*)(As + (wm*64 + mt*16 + l16)*72 + ks*32 + quad*8);
#pragma unroll
            for (int nt = 0; nt < 4; nt++)
                bfr[nt] = *(const bf16x8*)(Bs + (wn*64 + nt*16 + l16)*72 + ks*32 + quad*8);
#pragma unroll
            for (int mt = 0; mt < 4; mt++)
#pragma unroll
                for (int nt = 0; nt < 4; nt++)
                    acc[mt*4+nt] = __builtin_amdgcn_mfma_f32_16x16x32_bf16(af[mt], bfr[nt], acc[mt*4+nt], 0, 0, 0);
        }
    }
#pragma unroll
    for (int mt = 0; mt < 4; mt++)
#pragma unroll
        for (int nt = 0; nt < 4; nt++)
#pragma unroll
            for (int r = 0; r < 4; r++) {
                size_t rr = m0 + wm*64 + mt*16 + quad*4 + r;
                int cc = n0 + wn*64 + nt*16 + l16;
                if (outBf) Cb[rr*N + cc] = f2bf(acc[mt*4+nt][r]);
                else       Cf[rr*N + cc] = acc[mt*4+nt][r];
            }
}

// ---------------------------------------------------------------------------
// f32 GEMM for kv-proj (kept f32 for rmsnorm accuracy).
// ---------------------------------------------------------------------------
__global__ __launch_bounds__(256) void gemm_nt(const float* __restrict__ A,
                                               const float* __restrict__ Bm,
                                               float* __restrict__ Cm,
                                               int M, int N, int K,
                                               int lda, int ldb, int ldc)
{
    __shared__ float As[16][68];
    __shared__ float Bs[16][68];
    const int tid = threadIdx.x;
    const int m0 = blockIdx.y * 64, n0 = blockIdx.x * 64;
    const int lr = tid >> 2;
    const int lc = (tid & 3) << 2;
    const int ty = tid >> 4, tx = tid & 15;
    const float* Ag = A  + (m0 + lr) * lda + lc;
    const float* Bg = Bm + (n0 + lr) * ldb + lc;

    float acc[4][4];
#pragma unroll
    for (int i = 0; i < 4; i++)
#pragma unroll
        for (int j = 0; j < 4; j++) acc[i][j] = 0.f;

    for (int k0 = 0; k0 < K; k0 += 16) {
        float4 av = *(const float4*)(Ag + k0);
        float4 bv = *(const float4*)(Bg + k0);
        __syncthreads();
        As[lc+0][lr] = av.x; As[lc+1][lr] = av.y; As[lc+2][lr] = av.z; As[lc+3][lr] = av.w;
        Bs[lc+0][lr] = bv.x; Bs[lc+1][lr] = bv.y; Bs[lc+2][lr] = bv.z; Bs[lc+3][lr] = bv.w;
        __syncthreads();
#pragma unroll
        for (int kk = 0; kk < 16; kk++) {
            float4 a = *(const float4*)&As[kk][ty*4];
            float4 b = *(const float4*)&Bs[kk][tx*4];
            acc[0][0] += a.x*b.x; acc[0][1] += a.x*b.y; acc[0][2] += a.x*b.z; acc[0][3] += a.x*b.w;
            acc[1][0] += a.y*b.x; acc[1][1] += a.y*b.y; acc[1][2] += a.y*b.z; acc[1][3] += a.y*b.w;
            acc[2][0] += a.z*b.x; acc[2][1] += a.z*b.y; acc[2][2] += a.z*b.z; acc[2][3] += a.z*b.w;
            acc[3][0] += a.w*b.x; acc[3][1] += a.w*b.y; acc[3][2] += a.w*b.z; acc[3][3] += a.w*b.w;
        }
    }
#pragma unroll
    for (int i = 0; i < 4; i++) {
        float4 r; r.x = acc[i][0]; r.y = acc[i][1]; r.z = acc[i][2]; r.w = acc[i][3];
        *(float4*)(Cm + (m0 + ty*4 + i) * ldc + n0 + tx*4) = r;
    }
}

// ---------------------------------------------------------------------------
__global__ __launch_bounds__(256) void prep_wb(const float* __restrict__ wkv_b,
                                               ushort_t* __restrict__ wbkT,
                                               ushort_t* __restrict__ wbvB)
{
    int u = blockIdx.x * 256 + threadIdx.x;
    {
        int h = u >> 16, rem = u & 65535, c = rem >> 7, d = rem & 127;
        wbkT[u] = f2bf(wkv_b[h*131072 + d*512 + c]);
    }
    {
        int h = u >> 16, rem = u & 65535;
        wbvB[u] = f2bf(wkv_b[h*131072 + 65536 + rem]);
    }
}

// ---------------------------------------------------------------------------
__global__ __launch_bounds__(256) void kv_norm_rope(const float* __restrict__ kvr,
                                                    const float* __restrict__ w,
                                                    const float* __restrict__ cosT,
                                                    const float* __restrict__ sinT,
                                                    ushort_t* __restrict__ kvnb,
                                                    ushort_t* __restrict__ kvnT,
                                                    ushort_t* __restrict__ kpeb)
{
    const int bs   = blockIdx.x * 4 + (threadIdx.x >> 6);
    const int lane = threadIdx.x & 63;
    const int s    = bs & (S_ - 1);
    const float* row = kvr + bs * 576;

    float4 v0 = *(const float4*)(row + lane*8);
    float4 v1 = *(const float4*)(row + lane*8 + 4);
    float ss = v0.x*v0.x + v0.y*v0.y + v0.z*v0.z + v0.w*v0.w
             + v1.x*v1.x + v1.y*v1.y + v1.z*v1.z + v1.w*v1.w;
#pragma unroll
    for (int off = 32; off >= 1; off >>= 1) ss += __shfl_xor(ss, off);
    const float rs = rsqrtf(ss * (1.0f/512.0f) + 1e-6f);

    float4 w0 = *(const float4*)(w + lane*8);
    float4 w1 = *(const float4*)(w + lane*8 + 4);
    float o[8];
    o[0] = v0.x*rs*w0.x; o[1] = v0.y*rs*w0.y; o[2] = v0.z*rs*w0.z; o[3] = v0.w*rs*w0.w;
    o[4] = v1.x*rs*w1.x; o[5] = v1.y*rs*w1.y; o[6] = v1.z*rs*w1.z; o[7] = v1.w*rs*w1.w;

    ushort_t pk[8];
#pragma unroll
    for (int p = 0; p < 8; p++) pk[p] = f2bf(o[p]);
    *(uint4*)(kvnb + (size_t)bs*512 + lane*8) = *(const uint4*)pk;

    const int bb = bs >> 11, t = bs & 2047;
    ushort_t* base = kvnT + ((size_t)(bb*512 + lane*8))*2048 + t;
#pragma unroll
    for (int k = 0; k < 8; k++) base[k*2048] = pk[k];

    if (lane < 32) {
        float xr = row[512 + 2*lane], xi = row[512 + 2*lane + 1];
        float c  = cosT[s*32 + lane], sn = sinT[s*32 + lane];
        ushort_t p2[2] = { f2bf(xr*c - xi*sn), f2bf(xr*sn + xi*c) };
        *(uint_t*)(kpeb + (size_t)bs*64 + 2*lane) = *(const uint_t*)p2;
    }
}

// ---------------------------------------------------------------------------
// MFMA flash attention v4: static indexing + explicit barriers on every LDS
// write->read round-trip.
// ---------------------------------------------------------------------------
__global__ __launch_bounds__(512, 2) void attn_mfma(
    const ushort_t* __restrict__ qb,
    const ushort_t* __restrict__ kvnb,
    const ushort_t* __restrict__ kpeb,
    const ushort_t* __restrict__ kvnT,
    const float* __restrict__ cosT,
    const float* __restrict__ sinT,
    const ushort_t* __restrict__ wbkT,
    const ushort_t* __restrict__ wbvB,
    ushort_t* __restrict__ ovb)
{
    const int q0 = blockIdx.x * 64;
    const int h  = blockIdx.y;
    const int b  = blockIdx.z;
    const int tid  = threadIdx.x;
    const int wv   = tid >> 6;
    const int lane = tid & 63;
    const int l16  = lane & 15;
    const int quad = lane >> 4;
    const int rg   = wv >> 1;
    const int cg   = wv & 1;
    const float scale = 0.07216878364870323f;   // 192^-0.5

    __shared__ __align__(16) ushort_t lds[32384];   // 64768 B
    ushort_t* kt = lds;                 // 16 x 584
    ushort_t* vt = lds + 9344;          // 512 x 40 (t 0..15 data, 16..39 zero)
    ushort_t* pt = lds + 29824;         // 64 x 40

    const int mrowb = rg*16 + l16;
    const int sgr   = q0 + mrowb;
    const int irow  = rg*16 + quad*4;

    // ===== phase A: build Q A-frags qf[18] =====
    ushort_t* halfbuf = lds;            // 64 x 264 overlay (shorts 0..16895)
    ushort_t* qn = lds + 16896;         // 64 x 136 overlay (disjoint)

    for (int u = tid; u < 1024; u += 512) {
        int r = u >> 4, c8 = u & 15;
        *(uint4*)(qn + r*136 + c8*8) =
            *(const uint4*)(qb + (size_t)(b*S_ + q0 + r)*3072 + h*192 + c8*8);
    }
    __syncthreads();

    bf16x8 qa[4], qf[18];
#pragma unroll
    for (int ks = 0; ks < 4; ks++)
        qa[ks] = *(const bf16x8*)(qn + mrowb*136 + ks*32 + quad*8);

    const ushort_t* wbk_h = wbkT + h*65536;
#pragma unroll
    for (int half = 0; half < 2; half++) {
        f32x4 ab[16];
#pragma unroll
        for (int n = 0; n < 16; n++) ab[n] = (f32x4)(0.f);
#pragma unroll
        for (int n = 0; n < 16; n++) {
            const ushort_t* wp = wbk_h + (half*256 + n*16 + l16)*128 + quad*8;
#pragma unroll
            for (int ks = 0; ks < 4; ks++) {
                bf16x8 bw = *(const bf16x8*)(wp + ks*32);
                ab[n] = __builtin_amdgcn_mfma_f32_16x16x32_bf16(qa[ks], bw, ab[n], 0, 0, 0);
            }
        }
        __syncthreads();   // protect partner wave's reads of previous half (and qn for half 0)
#pragma unroll
        for (int n = 0; n < 16; n++)
#pragma unroll
            for (int r = 0; r < 4; r++)
                halfbuf[(irow + r)*264 + n*16 + l16] = f2bf(ab[n][r] * scale);
        __syncthreads();   // writes visible + ordered before reads
#pragma unroll
        for (int ks = 0; ks < 8; ks++)
            qf[half*8 + ks] = *(const bf16x8*)(halfbuf + mrowb*264 + ks*32 + quad*8);
    }

    // pe -> qf[16..17]
#pragma unroll
    for (int kk = 0; kk < 2; kk++) {
        int off = kk*32 + quad*8;
        uint4 pv4 = *(const uint4*)(qb + (size_t)(b*S_ + sgr)*3072 + h*192 + 128 + off);
        const ushort_t* pe = (const ushort_t*)&pv4;
        ushort_t pk[8];
#pragma unroll
        for (int u2 = 0; u2 < 4; u2++) {
            float xr = bf2f(pe[2*u2]), xi = bf2f(pe[2*u2+1]);
            int pi = (off >> 1) + u2;
            float c = cosT[sgr*32 + pi], sn = sinT[sgr*32 + pi];
            pk[2*u2]   = f2bf((xr*c  - xi*sn) * scale);
            pk[2*u2+1] = f2bf((xr*sn + xi*c ) * scale);
        }
        qf[16 + kk] = *(const bf16x8*)pk;
    }
    __syncthreads();   // all qf reads done; overlays may be reused

    // zero vt+pt region (pads stay zero)
    for (int u = tid; u < 11520; u += 512) ((uint_t*)lds)[4672 + u] = 0;
    __syncthreads();

    // ===== flash main loop, TK=16 =====
    f32x4 o[16];
#pragma unroll
    for (int n = 0; n < 16; n++) o[n] = (f32x4)(0.f);
    float m_s = -1e30f, l_s = 0.f;
    const int rglob = q0 + rg*16 + l16;
    const int lb = lane & 48;
    const int niter = (q0 >> 4) + 4;

#pragma unroll 1
    for (int it = 0; it < niter; it++) {
        const int t0 = it * 16;
        for (int u = tid; u < 1152; u += 512) {
            int j = u / 72, cc = u - j*72;
            const ushort_t* src = (cc < 64)
                ? (kvnb + (size_t)(b*S_ + t0 + j)*512 + cc*8)
                : (kpeb + (size_t)(b*S_ + t0 + j)*64 + (cc - 64)*8);
            *(uint4*)(kt + j*584 + cc*8) = *(const uint4*)src;
        }
        for (int u = tid; u < 1024; u += 512) {
            int c = u >> 1, part = u & 1;
            *(uint4*)(vt + c*40 + part*8) =
                *(const uint4*)(kvnT + (size_t)(b*512 + c)*2048 + t0 + part*8);
        }
        __syncthreads();

        // S^T[t][r] via mfma(A=K, B=Q)
        f32x4 s = (f32x4)(0.f);
#pragma unroll
        for (int ks = 0; ks < 18; ks++) {
            bf16x8 kf = *(const bf16x8*)(kt + l16*584 + ks*32 + quad*8);
            s = __builtin_amdgcn_mfma_f32_16x16x32_bf16(kf, qf[ks], s, 0, 0, 0);
        }

        // softmax over t for row rglob (lane: t = t0+quad*4+reg, r = l16)
        float pv[4];
        float mx = -1e30f;
#pragma unroll
        for (int reg = 0; reg < 4; reg++) {
            bool ok = (t0 + quad*4 + reg) <= rglob;
            pv[reg] = ok ? s[reg] : -1e30f;
            mx = fmaxf(mx, pv[reg]);
        }
        mx = fmaxf(mx, __shfl_xor(mx, 16));
        mx = fmaxf(mx, __shfl_xor(mx, 32));
        float mn = fmaxf(m_s, mx);
        float al = __expf(m_s - mn);
        m_s = mn;
        float ps = 0.f;
#pragma unroll
        for (int reg = 0; reg < 4; reg++) {
            pv[reg] = ((t0 + quad*4 + reg) <= rglob) ? __expf(pv[reg] - mn) : 0.f;
            ps += pv[reg];
        }
        ps += __shfl_xor(ps, 16);
        ps += __shfl_xor(ps, 32);
        l_s = l_s * al + ps;

        f32x4 alv;
#pragma unroll
        for (int reg = 0; reg < 4; reg++) alv[reg] = __shfl(al, lb + quad*4 + reg, 64);
#pragma unroll
        for (int n = 0; n < 16; n++) o[n] *= alv;

        // P^T -> pt[r][t], fence, read back A-frag (in-wave)
        ushort_t pk[4];
#pragma unroll
        for (int reg = 0; reg < 4; reg++) pk[reg] = f2bf(pv[reg]);
        *(uint2*)(pt + (rg*16 + l16)*40 + quad*4) = *(const uint2*)pk;
        asm volatile("" ::: "memory");   // forbid hoisting the read above the write
        bf16x8 ap = *(const bf16x8*)(pt + (rg*16 + l16)*40 + quad*8);

        // PV: o[n] += P[r][t] * V[t][c], c = cg*256 + n*16 + l16
#pragma unroll
        for (int n = 0; n < 16; n++) {
            bf16x8 bv = *(const bf16x8*)(vt + (cg*256 + n*16 + l16)*40 + quad*8);
            o[n] = __builtin_amdgcn_mfma_f32_16x16x32_bf16(ap, bv, o[n], 0, 0, 0);
        }
        __syncthreads();
    }

    // ===== epilogue: o_v = (o/l) @ wbv^T, barriers around obw round-trip =====
    float linv = 1.f / l_s;
    f32x4 rlv;
#pragma unroll
    for (int reg = 0; reg < 4; reg++) rlv[reg] = __shfl(linv, lb + quad*4 + reg, 64);

    const ushort_t* wbv_h = wbvB + h*65536;
    ushort_t* obw = lds + wv*2176;       // per-wave 16 x 136
    f32x4 acc2[8];
#pragma unroll
    for (int n = 0; n < 8; n++) acc2[n] = (f32x4)(0.f);

#pragma unroll
    for (int sub = 0; sub < 2; sub++) {
#pragma unroll
        for (int n = 0; n < 8; n++)
#pragma unroll
            for (int r = 0; r < 4; r++)
                obw[(quad*4 + r)*136 + n*16 + l16] = f2bf(o[sub*8 + n][r] * rlv[r]);
        __syncthreads();   // order writes before reads (and before next sub's overwrite)
#pragma unroll
        for (int ks = 0; ks < 4; ks++) {
            bf16x8 af = *(const bf16x8*)(obw + l16*136 + ks*32 + quad*8);
#pragma unroll
            for (int n2 = 0; n2 < 8; n2++) {
                bf16x8 bw = *(const bf16x8*)(wbv_h + (n2*16 + l16)*512 + cg*256 + sub*128 + ks*32 + quad*8);
                acc2[n2] = __builtin_amdgcn_mfma_f32_16x16x32_bf16(af, bw, acc2[n2], 0, 0, 0);
            }
        }
        __syncthreads();   // reads done before next overwrite / red overlay
    }

    float* red = (float*)lds;            // 64 x 132 f32 (overlays obw region)
    if (cg == 0) {
#pragma unroll
        for (int n2 = 0; n2 < 8; n2++)
#pragma unroll
            for (int r = 0; r < 4; r++)
                red[(irow + r)*132 + n2*16 + l16] = acc2[n2][r];
    }
    __syncthreads();
    if (cg == 1) {
#pragma unroll
        for (int n2 = 0; n2 < 8; n2++)
#pragma unroll
            for (int r = 0; r < 4; r++) {
                float v = red[(irow + r)*132 + n2*16 + l16] + acc2[n2][r];
                ovb[(size_t)(b*S_ + q0 + irow + r)*2048 + h*128 + n2*16 + l16] = f2bf(v);
            }
    }
}

// ---------------------------------------------------------------------------
extern "C" void kernel_launch(void* const* d_in, const int* in_sizes, int n_in,
                              void* d_out, int out_size, void* d_ws, size_t ws_size,
                              hipStream_t stream) {
    const float* x     = (const float*)d_in[0];
    const float* cosT  = (const float*)d_in[1];
    const float* sinT  = (const float*)d_in[2];
    // d_in[3] mask: unused (causality applied directly)
    const float* wq    = (const float*)d_in[4];
    const float* wkv_a = (const float*)d_in[5];
    const float* kvw   = (const float*)d_in[6];
    const float* wkv_b = (const float*)d_in[7];
    const float* wo    = (const float*)d_in[8];
    float* out = (float*)d_out;

    ushort_t* qb   = (ushort_t*)d_ws;       // 4096x3072 bf16
    ushort_t* xb   = qb   + 12582912;       // 4096x2048
    ushort_t* wqb  = xb   + 8388608;        // 3072x2048
    ushort_t* wob  = wqb  + 6291456;        // 2048x2048
    ushort_t* ovb  = wob  + 4194304;        // 4096x2048
    ushort_t* kvnb = ovb  + 8388608;        // 4096x512
    ushort_t* kpeb = kvnb + 2097152;        // 4096x64
    ushort_t* kvnT = kpeb + 262144;         // 2x512x2048
    ushort_t* wbkT = kvnT + 2097152;        // 16x512x128
    ushort_t* wbvB = wbkT + 1048576;        // 16x128x512
    float*    kvr  = (float*)(wbvB + 1048576);  // 4096x576 f32

    dim3 blk(256);
    cast_bf16<<<dim3(8192), blk, 0, stream>>>(x,  xb,  8388608);
    cast_bf16<<<dim3(6144), blk, 0, stream>>>(wq, wqb, 6291456);
    cast_bf16<<<dim3(4096), blk, 0, stream>>>(wo, wob, 4194304);
    prep_wb<<<dim3(4096), blk, 0, stream>>>(wkv_b, wbkT, wbvB);
    gemm_bf16<<<dim3(3072/128, 4096/128), blk, 0, stream>>>(xb, wqb, nullptr, qb, 4096, 3072, 2048, 1);
    gemm_nt<<<dim3(576/64, 4096/64), blk, 0, stream>>>(x, wkv_a, kvr, 4096, 576, 2048, 2048, 2048, 576);
    kv_norm_rope<<<dim3(4096/4), blk, 0, stream>>>(kvr, kvw, cosT, sinT, kvnb, kvnT, kpeb);
    attn_mfma<<<dim3(S_/64, H_, B_), dim3(512), 0, stream>>>(qb, kvnb, kpeb, kvnT, cosT, sinT, wbkT, wbvB, ovb);
    gemm_bf16<<<dim3(2048/128, 4096/128), blk, 0, stream>>>(ovb, wob, out, nullptr, 4096, 2048, 2048, 0);
}